// Round 1
// baseline (90.654 us; speedup 1.0000x reference)
//
#include <hip/hip_runtime.h>
#include <math.h>

#define NPTS 256
#define DIM 64
#define BATCH 4
#define EPSV 1e-6f

// ---------------------------------------------------------------------------
// euclid[b][i][j] = ||x_j - x_i||  (sqrt of sum of squared diffs, 0 if sq==0)
// grid: BATCH*64 blocks, 256 threads. Block handles 4 rows i; thread = col j.
// ---------------------------------------------------------------------------
__global__ __launch_bounds__(256) void euclid_kernel(
        const float* __restrict__ states, float* __restrict__ out) {
    const int b  = blockIdx.x >> 6;      // batch
    const int rg = blockIdx.x & 63;      // row group (4 rows)
    const int j  = threadIdx.x;
    const float* X = states + b * NPTS * DIM;

    // own column row in registers (64 floats)
    float4 xj[16];
    const float4* pj = (const float4*)(X + j * DIM);
#pragma unroll
    for (int q = 0; q < 16; ++q) xj[q] = pj[q];

#pragma unroll
    for (int r = 0; r < 4; ++r) {
        const int i = rg * 4 + r;
        const float4* pi = (const float4*)(X + i * DIM);  // wave-uniform
        float sq = 0.f;
#pragma unroll
        for (int q = 0; q < 16; ++q) {
            float4 a = pi[q];
            float dx = xj[q].x - a.x;
            float dy = xj[q].y - a.y;
            float dz = xj[q].z - a.z;
            float dw = xj[q].w - a.w;
            sq += dx * dx; sq += dy * dy; sq += dz * dz; sq += dw * dw;
        }
        out[b * NPTS * NPTS + i * NPTS + j] = (sq > 0.f) ? sqrtf(sq) : 0.f;
    }
}

// ---------------------------------------------------------------------------
// padic[i][j] = 3^{-v3(|i-j|)}  (0 on diagonal). v3(d) <= 5 for d<256 so the
// MAX_K=9 cap in the reference never binds.
// grid: 256 blocks x 256 threads, one entry each.
// ---------------------------------------------------------------------------
__global__ __launch_bounds__(256) void padic_kernel(float* __restrict__ out) {
    const int i = blockIdx.x;
    const int j = threadIdx.x;
    int d = i - j; if (d < 0) d = -d;
    float v;
    if (d == 0) {
        v = 0.f;
    } else {
        int pw = 1, dd = d;
        while (dd % 3 == 0) { pw *= 3; dd /= 3; }
        v = 1.0f / (float)pw;   // exact fp32 division, matches pow(3,-k) to <=1ulp
    }
    out[i * NPTS + j] = v;
}

// ---------------------------------------------------------------------------
// Violation count per batch: triples i<j<k where max > mid + EPS.
// One wave per (i,j) pair (grid-strided over q = i*256+j, skip j<=i, skip is
// wave-uniform). Lanes stride k>j: coalesced reads of rows i and j.
// grid: dim3(256, BATCH), 256 threads (4 waves/block).
// ---------------------------------------------------------------------------
__global__ __launch_bounds__(256) void ultra_kernel(
        const float* __restrict__ euclid, unsigned int* __restrict__ viol) {
    const int b = blockIdx.y;
    const float* D = euclid + b * NPTS * NPTS;
    const int lane  = threadIdx.x & 63;
    const int wave  = blockIdx.x * 4 + (threadIdx.x >> 6);
    const int nwav  = gridDim.x * 4;

    unsigned int cnt = 0;
    for (int q = wave; q < NPTS * NPTS; q += nwav) {
        const int i = q >> 8;
        const int j = q & 255;
        if (j <= i) continue;                    // wave-uniform branch
        const float a = D[q];                    // dij
        const float* rowi = D + i * NPTS;
        const float* rowj = D + j * NPTS;
        for (int k = j + 1 + lane; k < NPTS; k += 64) {
            const float bb = rowj[k];            // djk
            const float cc = rowi[k];            // dik
            const float mx = fmaxf(a, fmaxf(bb, cc));
            const float mn = fminf(a, fminf(bb, cc));
            const float mid = (((a + bb) + cc) - mx) - mn;  // mirror ref order
            cnt += (mx > mid + EPSV) ? 1u : 0u;
        }
    }

    __shared__ unsigned int red[256];
    red[threadIdx.x] = cnt;
    __syncthreads();
#pragma unroll
    for (int s = 128; s > 0; s >>= 1) {
        if ((int)threadIdx.x < s) red[threadIdx.x] += red[threadIdx.x + s];
        __syncthreads();
    }
    if (threadIdx.x == 0) atomicAdd(&viol[b], red[0]);
}

// ---------------------------------------------------------------------------
// ultra[b] = 1 - viol[b] / (n*(n-1)*(n-2)/6)
// ---------------------------------------------------------------------------
__global__ void finalize_kernel(const unsigned int* __restrict__ viol,
                                float* __restrict__ out) {
    const int t = threadIdx.x;
    if (t < BATCH) {
        out[t] = 1.0f - (float)viol[t] / 2763520.0f;  // 256*255*254/6, exact in fp32
    }
}

extern "C" void kernel_launch(void* const* d_in, const int* in_sizes, int n_in,
                              void* d_out, int out_size, void* d_ws, size_t ws_size,
                              hipStream_t stream) {
    const float* states = (const float*)d_in[0];
    float* out = (float*)d_out;
    float* out_euclid = out;                                   // 4*256*256
    float* out_padic  = out + BATCH * NPTS * NPTS;             // 256*256
    float* out_ultra  = out + BATCH * NPTS * NPTS + NPTS * NPTS; // 4
    unsigned int* viol = (unsigned int*)d_ws;

    hipMemsetAsync(d_ws, 0, BATCH * sizeof(unsigned int), stream);
    euclid_kernel<<<dim3(BATCH * 64), 256, 0, stream>>>(states, out_euclid);
    padic_kernel<<<dim3(NPTS), 256, 0, stream>>>(out_padic);
    ultra_kernel<<<dim3(256, BATCH), 256, 0, stream>>>(out_euclid, viol);
    finalize_kernel<<<1, 64, 0, stream>>>(viol, out_ultra);
}

// Round 2
// 85.211 us; speedup vs baseline: 1.0639x; 1.0639x over previous
//
#include <hip/hip_runtime.h>
#include <math.h>

#define NPTS 256
#define DIM 64
#define BATCH 4
#define EPSV 1e-6f
#define TOTAL_TRIPLES 2763520.0f  // 256*255*254/6, exact in fp32

// ---------------------------------------------------------------------------
// Kernel 1 (fused):
//   blocks [0,256):   euclid[b][i][j] = ||x_j - x_i||, 4 rows per block
//   blocks [256,320): padic rows (4 per block); block 256 also inits ultra=1.0
// ---------------------------------------------------------------------------
__global__ __launch_bounds__(256) void euclid_padic_kernel(
        const float* __restrict__ states, float* __restrict__ out_euclid,
        float* __restrict__ out_padic, float* __restrict__ out_ultra) {
    const int blk = blockIdx.x;
    const int j   = threadIdx.x;

    if (blk < BATCH * 64) {
        const int b  = blk >> 6;       // batch
        const int rg = blk & 63;       // row group (4 rows)
        const float* X = states + b * NPTS * DIM;

        float4 xj[16];
        const float4* pj = (const float4*)(X + j * DIM);
#pragma unroll
        for (int q = 0; q < 16; ++q) xj[q] = pj[q];

#pragma unroll
        for (int r = 0; r < 4; ++r) {
            const int i = rg * 4 + r;
            const float4* pi = (const float4*)(X + i * DIM);  // wave-uniform
            float sq = 0.f;
#pragma unroll
            for (int q = 0; q < 16; ++q) {
                float4 a = pi[q];
                float dx = xj[q].x - a.x;
                float dy = xj[q].y - a.y;
                float dz = xj[q].z - a.z;
                float dw = xj[q].w - a.w;
                sq += dx * dx; sq += dy * dy; sq += dz * dz; sq += dw * dw;
            }
            out_euclid[b * NPTS * NPTS + i * NPTS + j] = (sq > 0.f) ? sqrtf(sq) : 0.f;
        }
    } else {
        // padic: 4 rows per block
        const int rg = blk - BATCH * 64;
        if (rg == 0 && j < BATCH) out_ultra[j] = 1.0f;  // init for ultra atomics
#pragma unroll
        for (int r = 0; r < 4; ++r) {
            const int i = rg * 4 + r;
            int d = i - j; if (d < 0) d = -d;
            float v;
            if (d == 0) {
                v = 0.f;
            } else {
                int pw = 1, dd = d;
                while (dd % 3 == 0) { pw *= 3; dd /= 3; }
                v = 1.0f / (float)pw;   // exact: matches 3^-k to <=1 ulp
            }
            out_padic[i * NPTS + j] = v;
        }
    }
}

// ---------------------------------------------------------------------------
// Kernel 2: ultrametricity violations, finalize fused via float atomicAdd.
// One wave per (i,j) pair (grid-strided, wave-uniform skip of j<=i); lanes
// stride k>j so rowi[k]/rowj[k] reads are coalesced and L2-resident.
// Each block: LDS reduce -> atomicAdd(out_ultra[b], -cnt/total).
// ---------------------------------------------------------------------------
__global__ __launch_bounds__(256) void ultra_kernel(
        const float* __restrict__ euclid, float* __restrict__ out_ultra) {
    const int b = blockIdx.y;
    const float* D = euclid + b * NPTS * NPTS;
    const int lane  = threadIdx.x & 63;
    const int wave  = blockIdx.x * 4 + (threadIdx.x >> 6);
    const int nwav  = gridDim.x * 4;

    unsigned int cnt = 0;
    for (int q = wave; q < NPTS * NPTS; q += nwav) {
        const int i = q >> 8;
        const int j = q & 255;
        if (j <= i) continue;                    // wave-uniform branch
        const float a = D[q];                    // dij
        const float* rowi = D + i * NPTS;
        const float* rowj = D + j * NPTS;
        for (int k = j + 1 + lane; k < NPTS; k += 64) {
            const float bb = rowj[k];            // djk
            const float cc = rowi[k];            // dik
            const float mx = fmaxf(a, fmaxf(bb, cc));
            const float mn = fminf(a, fminf(bb, cc));
            const float mid = (((a + bb) + cc) - mx) - mn;  // mirror ref order
            cnt += (mx > mid + EPSV) ? 1u : 0u;
        }
    }

    __shared__ unsigned int red[256];
    red[threadIdx.x] = cnt;
    __syncthreads();
#pragma unroll
    for (int s = 128; s > 0; s >>= 1) {
        if ((int)threadIdx.x < s) red[threadIdx.x] += red[threadIdx.x + s];
        __syncthreads();
    }
    if (threadIdx.x == 0) {
        atomicAdd(&out_ultra[b], -(float)red[0] / TOTAL_TRIPLES);
    }
}

extern "C" void kernel_launch(void* const* d_in, const int* in_sizes, int n_in,
                              void* d_out, int out_size, void* d_ws, size_t ws_size,
                              hipStream_t stream) {
    const float* states = (const float*)d_in[0];
    float* out = (float*)d_out;
    float* out_euclid = out;                                     // 4*256*256
    float* out_padic  = out + BATCH * NPTS * NPTS;               // 256*256
    float* out_ultra  = out + BATCH * NPTS * NPTS + NPTS * NPTS; // 4

    euclid_padic_kernel<<<dim3(BATCH * 64 + 64), 256, 0, stream>>>(
        states, out_euclid, out_padic, out_ultra);
    ultra_kernel<<<dim3(256, BATCH), 256, 0, stream>>>(out_euclid, out_ultra);
}